// Round 15
// baseline (6494.842 us; speedup 1.0000x reference)
//
#include <hip/hip_runtime.h>
#include <hip/hip_cooperative_groups.h>
#include <cstdint>
#include <cstddef>

#define TT 128
#define BB 64
#define EE 256
#define HH 1024
#define VV 8000
#define LSTRIDE 132   // LDS row stride: 16B-aligned, 4i-bank starts (optimal b128)

// ---------------- threefry2x32 (20 rounds), bit-exact vs JAX partitionable ----------------
__device__ __forceinline__ uint32_t rotl32(uint32_t v, int r){ return (v<<r)|(v>>(32-r)); }

__device__ __forceinline__ void tf2x32(uint32_t k0, uint32_t k1, uint32_t x0, uint32_t x1,
                                       uint32_t& y0, uint32_t& y1)
{
  const uint32_t k2 = k0 ^ k1 ^ 0x1BD11BDAu;
  x0 += k0; x1 += k1;
#define TFR(r) { x0 += x1; x1 = rotl32(x1,(r)); x1 ^= x0; }
  TFR(13) TFR(15) TFR(26) TFR(6)   x0 += k1; x1 += k2 + 1u;
  TFR(17) TFR(29) TFR(16) TFR(24)  x0 += k2; x1 += k0 + 2u;
  TFR(13) TFR(15) TFR(26) TFR(6)   x0 += k0; x1 += k1 + 3u;
  TFR(17) TFR(29) TFR(16) TFR(24)  x0 += k1; x1 += k2 + 4u;
  TFR(13) TFR(15) TFR(26) TFR(6)   x0 += k2; x1 += k0 + 5u;
#undef TFR
  y0 = x0; y1 = x1;
}

// uniform in [tiny,1): bit-exact fp32 recipe of jax uniform(minval=tiny, maxval=1)
__device__ __forceinline__ float u01f(uint32_t bits){
  float f = __uint_as_float((bits >> 9) | 0x3f800000u) - 1.0f;
  return (f == 0.0f) ? 1.17549435e-38f : f;
}

// ---------------- XLA EmitFastTanh, non-FMA form (mul/add separate roundings) ------------
__device__ __forceinline__ float xla_tanh(float x){
  float xc = fminf(fmaxf(x, -7.90531110763549805f), 7.90531110763549805f);
  float x2 = __fmul_rn(xc, xc);
  float num = -2.76076847742355e-16f;
  num = __fadd_rn(__fmul_rn(x2, num),  2.00018790482477e-13f);
  num = __fadd_rn(__fmul_rn(x2, num), -8.60467152213735e-11f);
  num = __fadd_rn(__fmul_rn(x2, num),  5.12229709037114e-08f);
  num = __fadd_rn(__fmul_rn(x2, num),  1.48572235717979e-05f);
  num = __fadd_rn(__fmul_rn(x2, num),  6.37261928875436e-04f);
  num = __fadd_rn(__fmul_rn(x2, num),  4.89352455891786e-03f);
  num = __fmul_rn(xc, num);
  float den = 1.19825839466702e-06f;
  den = __fadd_rn(__fmul_rn(x2, den), 1.18534705686654e-04f);
  den = __fadd_rn(__fmul_rn(x2, den), 2.26843463243900e-03f);
  den = __fadd_rn(__fmul_rn(x2, den), 4.89352518554385e-03f);
  float r = __fdiv_rn(num, den);
  return (fabsf(x) < 0.0004f) ? x : r;
}

// XLA LogisticExpander: logistic(x) = 0.5 + 0.5*tanh(0.5*x), separate roundings
__device__ __forceinline__ float xla_sigmoid(float x){
  float t = xla_tanh(__fmul_rn(0.5f, x));
  return __fadd_rn(0.5f, __fmul_rn(0.5f, t));
}

// pack fp32 score + v; ties -> smaller v (first-max, matching jnp.argmax)
__device__ __forceinline__ unsigned long long pack32(float s, int v){
  uint32_t u = __float_as_uint(s);
  u = (u >> 31) ? ~u : (u | 0x80000000u);
  return ((unsigned long long)u << 32) | (unsigned)(8191 - v);
}

#define LGKM0 asm volatile("s_waitcnt lgkmcnt(0)" ::: "memory")

// ---------------- init ----------------
__global__ void initz(float* hfull, unsigned long long* best, int* flags){
  int i = blockIdx.x*256 + threadIdx.x;
  if (i < HH*BB)  hfull[i] = 0.f;          // slot 0 = h(-1) = 0
  if (i < TT*BB)  best[i] = 0ull;
  if (i < 256)    flags[i] = 0;
}

// ---------------- px precompute, TRANSPOSED 16-lane-grouped layout (R13-verified) ---------
// pxT[t][b>>4][e>>2][b&15][4]: float idx = ((((t*4+(b>>4))*64 + (e>>2))*16 + (b&15))*4 + (e&3)
// Thread b reads its own px row as float4 (per-16-lane group = 256B contiguous segments).
__global__ __launch_bounds__(256) void pxgen(
    const int* __restrict__ x, const float* __restrict__ emb, float* __restrict__ pxT)
{
  int flat = blockIdx.x*256 + threadIdx.x;      // 128*64*256 = 2M
  int e = flat & 255;
  int b = (flat >> 8) & 63;
  int t = flat >> 14;
  if (t >= TT) return;
  int tok = x[b*TT + t];
  size_t fi = ((((size_t)t*4 + (b>>4))*64 + (e>>2))*16 + (size_t)(b&15))*4 + (e&3);
  pxT[fi] = emb[(size_t)tok*EE + e];
}

// ---------------- transpose 4 gate matrices: in [R][C] -> out[(g*C + c)*R + r] ----------------
__global__ __launch_bounds__(256) void transpose4f(
    const float* __restrict__ g0, const float* __restrict__ g1,
    const float* __restrict__ g2, const float* __restrict__ g3,
    float* __restrict__ out, int R, int C)
{
  const float* in = (blockIdx.y==0)?g0:(blockIdx.y==1)?g1:(blockIdx.y==2)?g2:g3;
  int tilesC = C >> 6;
  int tr = blockIdx.x / tilesC, tc = blockIdx.x % tilesC;
  __shared__ float tile[64][65];
  int tid = threadIdx.x;
  #pragma unroll
  for (int s = 0; s < 16; ++s) {
    int li = s*256 + tid;
    int r = li >> 6, c = li & 63;
    tile[r][c] = in[(size_t)(tr*64 + r)*C + tc*64 + c];
  }
  __syncthreads();
  #pragma unroll
  for (int s = 0; s < 16; ++s) {
    int li = s*256 + tid;
    int c = li >> 6, r = li & 63;
    out[((size_t)blockIdx.y*C + tc*64 + c)*R + tr*64 + r] = tile[r][c];
  }
}

// ---------------- cooperative LSTM recurrence: panel-split k + register-direct xw ---------
// R15 = R14 (verified: kh panel-split hU, 4.98ms steady) with the xw path switched to
// R13's VERIFIED register-direct pxT loop: px is producer-transposed (pxgen), so each
// thread reads its own row as float4s -- the spx LDS staging (512 writes + 512 reads +
// 4 barriers per step) disappears. px slot/step = 64KB (L2-resident); the 8x per-CU
// wave redundancy (~512KB/CU/step) is L1/L2-served and overlappable, cheaper than the
// removed LDS instrs + barrier convoys (R13 proved this layout correct; its regression
// was the h-path's 4x-larger redundancy, not px). hU/exchange/transport/poll = R14
// byte-identical. LDS drops to ~77KB.
__global__ __launch_bounds__(512) void lstm_rec(
    const float* __restrict__ Wt, const float* __restrict__ Ut,
    const float* __restrict__ bi, const float* __restrict__ bf,
    const float* __restrict__ bog, const float* __restrict__ bc,
    const float* __restrict__ pxT, float* __restrict__ hfull,
    int* __restrict__ flags)
{
  __shared__ float sA[64*LSTRIDE];
  __shared__ float sB[64*LSTRIDE];
  __shared__ float xch[2304];   // [0..1023] kh1->kh0 P2/P3 g0,g1 | [1024..1535] kh0->kh1 tA g2,g3
                                // [1536..2047] th/ogs exchange

  const int tid  = threadIdx.x;
  const int w    = tid >> 6;
  const int lane = tid & 63;
  const int p    = w & 3;                  // j-column 0..3
  const int kh   = w >> 2;                 // k-half: 0 = panels P0,P1 (k<576), 1 = P2,P3
  const int ju   = __builtin_amdgcn_readfirstlane(blockIdx.x*4 + p);
  const int sw4  = ((lane >> 3) & 7) << 2; // read-side column swizzle for row=lane
  const int lgrp = lane >> 4, l16 = lane & 15;

  // U rows for ALL 4 gates (uniform per wave -> scalar regs)
  const float* Ug0 = Ut + ((size_t)0*HH + ju)*HH;
  const float* Ug1 = Ut + ((size_t)1*HH + ju)*HH;
  const float* Ug2 = Ut + ((size_t)2*HH + ju)*HH;
  const float* Ug3 = Ut + ((size_t)3*HH + ju)*HH;
  // xw rows for my finalized gate pair (kh0: i,f ; kh1: og,c~)
  const int g0 = 2*kh, g1 = 2*kh + 1;
  const float* W0 = Wt + ((size_t)g0*HH + ju)*EE;
  const float* W1 = Wt + ((size_t)g1*HH + ju)*EE;
  const float biaA = kh ? bog[ju] : bi[ju];
  const float biaB = kh ? bc[ju]  : bf[ju];

  float c = 0.f;
  float B0 = 0.f, B1 = 0.f;   // xw+bias for my 2 finalized gates
  float4 pre[4];

  auto load_chunk = [&](const float* hp, int hcn){
    #pragma unroll
    for (int s = 0; s < 4; ++s) {
      int f = s*512 + tid;
      int k = f >> 4, b0 = (f & 15)*4;
      pre[s] = *(const float4*)(hp + (size_t)(hcn*128 + k)*BB + b0);
    }
  };
  auto store_chunk = [&](float* buf){
    #pragma unroll
    for (int s = 0; s < 4; ++s) {
      int f = s*512 + tid;
      int k = f >> 4, b0 = (f & 15)*4;
      int kc = k ^ (((b0 >> 3) & 7) << 2);
      buf[(b0+0)*LSTRIDE + kc] = pre[s].x;
      buf[(b0+1)*LSTRIDE + kc] = pre[s].y;
      buf[(b0+2)*LSTRIDE + kc] = pre[s].z;
      buf[(b0+3)*LSTRIDE + kc] = pre[s].w;
    }
  };

  // xw chains for my 2 gates at step t2: register-direct from pxT (R13-verified loop);
  // exact e=0..255 mul/add order, then +bias
  auto compute_xw = [&](int t2){
    float A0 = 0.f, A1 = 0.f;
    const float4* pb = (const float4*)pxT + (((size_t)t2*4 + lgrp)*64)*16 + l16;
    #pragma unroll 1
    for (int ec = 0; ec < 8; ++ec) {
      #pragma unroll
      for (int j = 0; j < 8; ++j) {
        int eq = ec*8 + j;
        float4 v = pb[(size_t)eq*16];
        int e = eq*4;
        A0 = __fadd_rn(A0, __fmul_rn(v.x, W0[e+0]));
        A1 = __fadd_rn(A1, __fmul_rn(v.x, W1[e+0]));
        A0 = __fadd_rn(A0, __fmul_rn(v.y, W0[e+1]));
        A1 = __fadd_rn(A1, __fmul_rn(v.y, W1[e+1]));
        A0 = __fadd_rn(A0, __fmul_rn(v.z, W0[e+2]));
        A1 = __fadd_rn(A1, __fmul_rn(v.z, W1[e+2]));
        A0 = __fadd_rn(A0, __fmul_rn(v.w, W0[e+3]));
        A1 = __fadd_rn(A1, __fmul_rn(v.w, W1[e+3]));
      }
    }
    B0 = __fadd_rn(A0, biaA);
    B1 = __fadd_rn(A1, biaB);
  };

  compute_xw(0);   // prologue: xw for t=0

  #pragma unroll 1
  for (int t = 0; t < TT; ++t) {
    const float* hp = hfull + (size_t)t*(HH*BB);        // h(t-1), write-once slot
    float*       rn = hfull + (size_t)(t+1)*(HH*BB);    // h(t) destination

    // ---- h @ U: panel-split MAC, all 4 gates per thread over my k-half ----
    load_chunk(hp, 0);
    float R0=0.f, R1=0.f, R2=0.f, R3=0.f;       // running panel chains (4 gates)
    float PA0=0.f, PA1=0.f, PA2=0.f, PA3=0.f;   // saved first panel of my half
    #pragma unroll 1
    for (int hc = 0; hc < 8; ++hc) {
      float* cur = (hc & 1) ? sB : sA;
      store_chunk(cur);                    // waits pre deps (counted vmcnt, not 0)
      if (hc < 7) load_chunk(hp, hc + 1);  // prefetch stays in flight across barrier
      LGKM0;                               // staging writes retired
      __builtin_amdgcn_s_barrier();        // (WAR on cur guaranteed by bar(hc-1))
      // my sub-range: kh0 -> k<576 (chunks 0..3 full, chunk4 subs 0,1);
      //               kh1 -> k>=576 (chunk4 subs 2,3, chunks 5..7 full)
      int sLo = kh ? ((hc == 4) ? 2 : (hc > 4 ? 0 : 4)) : 0;
      int sHi = kh ? ((hc >= 4) ? 4 : 0)               : ((hc < 4) ? 4 : (hc == 4 ? 2 : 0));
      #pragma unroll
      for (int sub = 0; sub < 4; ++sub) {
        if (sub < sLo || sub >= sHi) continue;     // wave-uniform guard
        int kabs = hc*128 + sub*32;
        if (kabs == 288 || kabs == 864) {          // end of my half's first panel
          PA0 = R0; R0 = 0.f;
          PA1 = R1; R1 = 0.f;
          PA2 = R2; R2 = 0.f;
          PA3 = R3; R3 = 0.f;
        }
        #pragma unroll
        for (int q = sub*32; q < sub*32 + 32; q += 4) {
          float4 h4 = *(const float4*)&cur[lane*LSTRIDE + (q ^ sw4)];
          int k = hc*128 + q;
          R0 = __fadd_rn(R0, __fmul_rn(h4.x, Ug0[k+0]));
          R1 = __fadd_rn(R1, __fmul_rn(h4.x, Ug1[k+0]));
          R2 = __fadd_rn(R2, __fmul_rn(h4.x, Ug2[k+0]));
          R3 = __fadd_rn(R3, __fmul_rn(h4.x, Ug3[k+0]));
          R0 = __fadd_rn(R0, __fmul_rn(h4.y, Ug0[k+1]));
          R1 = __fadd_rn(R1, __fmul_rn(h4.y, Ug1[k+1]));
          R2 = __fadd_rn(R2, __fmul_rn(h4.y, Ug2[k+1]));
          R3 = __fadd_rn(R3, __fmul_rn(h4.y, Ug3[k+1]));
          R0 = __fadd_rn(R0, __fmul_rn(h4.z, Ug0[k+2]));
          R1 = __fadd_rn(R1, __fmul_rn(h4.z, Ug1[k+2]));
          R2 = __fadd_rn(R2, __fmul_rn(h4.z, Ug2[k+2]));
          R3 = __fadd_rn(R3, __fmul_rn(h4.z, Ug3[k+2]));
          R0 = __fadd_rn(R0, __fmul_rn(h4.w, Ug0[k+3]));
          R1 = __fadd_rn(R1, __fmul_rn(h4.w, Ug1[k+3]));
          R2 = __fadd_rn(R2, __fmul_rn(h4.w, Ug2[k+3]));
          R3 = __fadd_rn(R3, __fmul_rn(h4.w, Ug3[k+3]));
        }
      }
    }
    // ---- exchange A: assemble T per gate in exact fold order ----
    float keepA = 0.f, keepB = 0.f, keepC = 0.f, keepD = 0.f;
    if (kh == 0) {
      keepA = __fadd_rn(PA0, R0);       // tA g0
      keepB = __fadd_rn(PA1, R1);       // tA g1
      xch[1024 + p*64 + lane] = __fadd_rn(PA2, R2);   // tA g2
      xch[1280 + p*64 + lane] = __fadd_rn(PA3, R3);   // tA g3
    } else {
      keepA = PA2; keepB = R2;          // P2,P3 g2
      keepC = PA3; keepD = R3;          // P2,P3 g3
      xch[   0 + p*64 + lane] = PA0;    // P2 g0
      xch[ 256 + p*64 + lane] = R0;     // P3 g0
      xch[ 512 + p*64 + lane] = PA1;    // P2 g1
      xch[ 768 + p*64 + lane] = R1;     // P3 g1
    }
    LGKM0;
    __builtin_amdgcn_s_barrier();       // exchange A visible
    float z0, z1;
    if (kh == 0) {
      float T0 = __fadd_rn(__fadd_rn(keepA, xch[   0 + p*64 + lane]), xch[ 256 + p*64 + lane]);
      float T1 = __fadd_rn(__fadd_rn(keepB, xch[ 512 + p*64 + lane]), xch[ 768 + p*64 + lane]);
      z0 = __fadd_rn(B0, T0);           // gate i
      z1 = __fadd_rn(B1, T1);           // gate f
    } else {
      float T2 = __fadd_rn(__fadd_rn(xch[1024 + p*64 + lane], keepA), keepB);
      float T3 = __fadd_rn(__fadd_rn(xch[1280 + p*64 + lane], keepC), keepD);
      z0 = __fadd_rn(B0, T2);           // gate og
      z1 = __fadd_rn(B1, T3);           // gate c~
    }

    // ---- gates: kh1 computes tanh(zc), sig(zo); kh0 computes sig(zi), sig(zf) ----
    float igv = 0.f, fgv = 0.f, hv = 0.f;
    if (kh) {
      float th  = xla_tanh(z1);
      float ogs = xla_sigmoid(z0);
      xch[1536 + p*64 + lane] = th;
      xch[1792 + p*64 + lane] = ogs;
    } else {
      igv = xla_sigmoid(z0);
      fgv = xla_sigmoid(z1);
    }
    LGKM0;
    __builtin_amdgcn_s_barrier();           // th/ogs visible (LDS-only hazard)
    if (!kh) {
      float th  = xch[1536 + p*64 + lane];
      float ogs = xch[1792 + p*64 + lane];
      c = __fadd_rn(__fmul_rn(fgv, c), __fmul_rn(igv, th));
      hv = __fmul_rn(ogs, xla_tanh(c));
      __hip_atomic_store(&rn[(size_t)ju*BB + lane], hv,
                         __ATOMIC_RELAXED, __HIP_MEMORY_SCOPE_AGENT);
    }
    __syncthreads();   // REQUIRED vmcnt(0) drain: all waves' h stores done before flag
    if (tid == 0)
      __hip_atomic_store(&flags[blockIdx.x], t+1, __ATOMIC_RELEASE, __HIP_MEMORY_SCOPE_AGENT);

    if (t < TT-1) {
      compute_xw(t+1);    // overlapped with other blocks finishing step t
      if (w == 0) {       // wave0 polls all 256 flags (4 per lane)
        for (;;) {
          int m0 = __hip_atomic_load(&flags[lane],       __ATOMIC_RELAXED, __HIP_MEMORY_SCOPE_AGENT);
          int m1 = __hip_atomic_load(&flags[64 + lane],  __ATOMIC_RELAXED, __HIP_MEMORY_SCOPE_AGENT);
          int m2 = __hip_atomic_load(&flags[128 + lane], __ATOMIC_RELAXED, __HIP_MEMORY_SCOPE_AGENT);
          int m3 = __hip_atomic_load(&flags[192 + lane], __ATOMIC_RELAXED, __HIP_MEMORY_SCOPE_AGENT);
          int mm = m0 < m1 ? m0 : m1;
          int nn = m2 < m3 ? m2 : m3;
          mm = mm < nn ? mm : nn;
          if (__all(mm >= t+1)) break;
          __builtin_amdgcn_s_sleep(1);
        }
        __atomic_signal_fence(__ATOMIC_ACQUIRE);
      }
      __syncthreads();
    }
  }
}

// ---------------- logits + gumbel argmax: XLA-CPU faithful (reads hfull slot t+1) -------
__global__ __launch_bounds__(256, 2) void logits_samp(
    const float* __restrict__ hfull, const float* __restrict__ Wo,
    const float* __restrict__ bo, const int* __restrict__ gnp,
    unsigned long long* __restrict__ best)
{
  const int t = 64 + blockIdx.y;
  if (t < gnp[0]) return;
  const int vt   = blockIdx.x;     // [0,8)
  const int z    = blockIdx.z;     // [0,4) b-quarter
  const int tid  = threadIdx.x;
  const int w    = tid >> 6;
  const int lane = tid & 63;

  int v[4], vc[4]; bool val[4];
  #pragma unroll
  for (int vj = 0; vj < 4; ++vj) {
    v[vj]  = vt*1024 + vj*256 + tid;
    val[vj] = (v[vj] < VV);
    vc[vj] = val[vj] ? v[vj] : (VV-1);
  }

  __shared__ float hds[128*16];
  __shared__ unsigned long long red[4][16];

  float tot[64], reg[64];
  #pragma unroll
  for (int i = 0; i < 64; ++i) { tot[i] = 0.f; reg[i] = 0.f; }

  const float* hf = hfull + (size_t)(t+1)*(HH*BB);   // h(t) lives in slot t+1

  #pragma unroll 1
  for (int kc8 = 0; kc8 < 8; ++kc8) {
    __syncthreads();
    #pragma unroll
    for (int s = 0; s < 8; ++s) {
      int idx = s*256 + tid;
      int kl = idx >> 4, bb = idx & 15;
      hds[idx] = hf[(size_t)(kc8*128 + kl)*BB + z*16 + bb];
    }
    __syncthreads();
    #pragma unroll 1
    for (int sub = 0; sub < 4; ++sub) {
      int kabs = kc8*128 + sub*32;
      if (kabs == 288 || kabs == 576 || kabs == 864) {
        #pragma unroll
        for (int i = 0; i < 64; ++i) { tot[i] = __fadd_rn(tot[i], reg[i]); reg[i] = 0.f; }
      }
      #pragma unroll 2
      for (int k = sub*32; k < sub*32 + 32; ++k) {
        const float* wr = Wo + (size_t)(kc8*128 + k)*VV;
        float wv0 = wr[vc[0]], wv1 = wr[vc[1]], wv2 = wr[vc[2]], wv3 = wr[vc[3]];
        #pragma unroll
        for (int bb = 0; bb < 16; ++bb) {
          float hb = hds[k*16 + bb];
          reg[0*16+bb] = __fadd_rn(reg[0*16+bb], __fmul_rn(hb, wv0));
          reg[1*16+bb] = __fadd_rn(reg[1*16+bb], __fmul_rn(hb, wv1));
          reg[2*16+bb] = __fadd_rn(reg[2*16+bb], __fmul_rn(hb, wv2));
          reg[3*16+bb] = __fadd_rn(reg[3*16+bb], __fmul_rn(hb, wv3));
        }
      }
    }
  }
  #pragma unroll
  for (int i = 0; i < 64; ++i) tot[i] = __fadd_rn(tot[i], reg[i]);

  uint32_t kt0, kt1;
  tf2x32(0u, 1u, 0u, (uint32_t)t, kt0, kt1);
  float bov[4];
  #pragma unroll
  for (int vj = 0; vj < 4; ++vj) bov[vj] = val[vj] ? bo[v[vj]] : 0.f;

  #pragma unroll 1
  for (int bb = 0; bb < 16; ++bb) {
    int bglob = z*16 + bb;
    unsigned long long pm = 0ull;
    #pragma unroll
    for (int vj = 0; vj < 4; ++vj) {
      if (val[vj]) {
        uint32_t y0, y1;
        tf2x32(kt0, kt1, 0u, (uint32_t)(bglob*VV + v[vj]), y0, y1);
        float u  = u01f(y0 ^ y1);
        float l1 = logf(u);
        float l2 = logf(-l1);
        float g  = -l2;
        float L  = __fadd_rn(tot[vj*16 + bb], bov[vj]);
        float sc = __fadd_rn(g, L);
        unsigned long long pk = pack32(sc, v[vj]);
        if (pk > pm) pm = pk;
      }
    }
    #pragma unroll
    for (int m = 32; m > 0; m >>= 1) {
      unsigned long long q = __shfl_xor(pm, m);
      if (q > pm) pm = q;
    }
    if (lane == 0) red[w][bb] = pm;
    __syncthreads();
    if (tid == 0) {
      unsigned long long m0 = red[0][bb];
      if (red[1][bb] > m0) m0 = red[1][bb];
      if (red[2][bb] > m0) m0 = red[2][bb];
      if (red[3][bb] > m0) m0 = red[3][bb];
      atomicMax(&best[(size_t)t*BB + z*16 + bb], m0);
    }
    __syncthreads();
  }
}

// ---------------- finalize ----------------
__global__ void finalize(const int* __restrict__ x, const int* __restrict__ gnp,
                         const unsigned long long* __restrict__ best, int* __restrict__ out)
{
  int i = blockIdx.x*256 + threadIdx.x;
  if (i >= BB*TT) return;
  int t = i & 127;
  int b = i >> 7;
  if (t < gnp[0] || t < 64) out[i] = x[i];
  else out[i] = 8191 - (int)(best[(size_t)t*BB + b] & 0x1FFFull);
}

// ---------------- launch ----------------
extern "C" void kernel_launch(void* const* d_in, const int* in_sizes, int n_in,
                              void* d_out, int out_size, void* d_ws, size_t ws_size,
                              hipStream_t stream)
{
  const int*   x    = (const int*)  d_in[0];
  const int*   gn   = (const int*)  d_in[1];
  const float* emb  = (const float*)d_in[2];
  const float* Wi   = (const float*)d_in[3];
  const float* Ui   = (const float*)d_in[4];
  const float* bi   = (const float*)d_in[5];
  const float* Wf   = (const float*)d_in[6];
  const float* Uf   = (const float*)d_in[7];
  const float* bf   = (const float*)d_in[8];
  const float* Wog  = (const float*)d_in[9];
  const float* Uog  = (const float*)d_in[10];
  const float* bog  = (const float*)d_in[11];
  const float* Wc   = (const float*)d_in[12];
  const float* Uc   = (const float*)d_in[13];
  const float* bc   = (const float*)d_in[14];
  const float* Wo   = (const float*)d_in[15];
  const float* bo   = (const float*)d_in[16];

  // ws: Ut 16MB | Wt 4MB | hfull 32.25MB (129 write-once h slots; doubles as hist)
  //     | pxT 8MB | best 64KB | flags 1KB   (~60.3MB total)
  float* Ut    = (float*)d_ws;                             // 4Mi floats
  float* Wt    = Ut + (size_t)4*1024*1024;                 // 1Mi floats
  float* hfull = Wt + (size_t)1024*1024;                   // 129*65536 floats
  float* pxT   = hfull + (size_t)(TT+1)*HH*BB;             // 128*256*64 floats
  unsigned long long* best =
      (unsigned long long*)(pxT + (size_t)TT*EE*BB);       // 8192 u64
  int* flags  = (int*)(best + (size_t)TT*BB);              // 256 int

  initz<<<512, 256, 0, stream>>>(hfull, best, flags);
  transpose4f<<<dim3(256,4), 256, 0, stream>>>(Ui, Uf, Uog, Uc, Ut, 1024, 1024);
  transpose4f<<<dim3(64,4),  256, 0, stream>>>(Wi, Wf, Wog, Wc, Wt, 256, 1024);
  pxgen<<<8192, 256, 0, stream>>>(x, emb, pxT);

  const float* Wtp = Wt; const float* Utp = Ut;
  const float* bip = bi; const float* bfp = bf; const float* bogp = bog; const float* bcp = bc;
  const float* pxp = pxT; float* hfullp = hfull; int* flagsp = flags;
  void* kargs[] = { (void*)&Wtp, (void*)&Utp,
                    (void*)&bip, (void*)&bfp, (void*)&bogp, (void*)&bcp,
                    (void*)&pxp, (void*)&hfullp, (void*)&flagsp };
  hipLaunchCooperativeKernel((void*)lstm_rec, dim3(256), dim3(512), kargs, 0, stream);

  logits_samp<<<dim3(8,64,4), 256, 0, stream>>>(hfull, Wo, bo, gn, best);
  finalize<<<32, 256, 0, stream>>>(x, gn, best, (int*)d_out);
}

// Round 16
// 6232.758 us; speedup vs baseline: 1.0420x; 1.0420x over previous
//
#include <hip/hip_runtime.h>
#include <hip/hip_cooperative_groups.h>
#include <cstdint>
#include <cstddef>

#define TT 128
#define BB 64
#define EE 256
#define HH 1024
#define VV 8000
#define LSTRIDE 132   // LDS row stride: 16B-aligned, 4i-bank starts (optimal b128)

// ---------------- threefry2x32 (20 rounds), bit-exact vs JAX partitionable ----------------
__device__ __forceinline__ uint32_t rotl32(uint32_t v, int r){ return (v<<r)|(v>>(32-r)); }

__device__ __forceinline__ void tf2x32(uint32_t k0, uint32_t k1, uint32_t x0, uint32_t x1,
                                       uint32_t& y0, uint32_t& y1)
{
  const uint32_t k2 = k0 ^ k1 ^ 0x1BD11BDAu;
  x0 += k0; x1 += k1;
#define TFR(r) { x0 += x1; x1 = rotl32(x1,(r)); x1 ^= x0; }
  TFR(13) TFR(15) TFR(26) TFR(6)   x0 += k1; x1 += k2 + 1u;
  TFR(17) TFR(29) TFR(16) TFR(24)  x0 += k2; x1 += k0 + 2u;
  TFR(13) TFR(15) TFR(26) TFR(6)   x0 += k0; x1 += k1 + 3u;
  TFR(17) TFR(29) TFR(16) TFR(24)  x0 += k1; x1 += k2 + 4u;
  TFR(13) TFR(15) TFR(26) TFR(6)   x0 += k2; x1 += k0 + 5u;
#undef TFR
  y0 = x0; y1 = x1;
}

// uniform in [tiny,1): bit-exact fp32 recipe of jax uniform(minval=tiny, maxval=1)
__device__ __forceinline__ float u01f(uint32_t bits){
  float f = __uint_as_float((bits >> 9) | 0x3f800000u) - 1.0f;
  return (f == 0.0f) ? 1.17549435e-38f : f;
}

// ---------------- XLA EmitFastTanh, non-FMA form (mul/add separate roundings) ------------
__device__ __forceinline__ float xla_tanh(float x){
  float xc = fminf(fmaxf(x, -7.90531110763549805f), 7.90531110763549805f);
  float x2 = __fmul_rn(xc, xc);
  float num = -2.76076847742355e-16f;
  num = __fadd_rn(__fmul_rn(x2, num),  2.00018790482477e-13f);
  num = __fadd_rn(__fmul_rn(x2, num), -8.60467152213735e-11f);
  num = __fadd_rn(__fmul_rn(x2, num),  5.12229709037114e-08f);
  num = __fadd_rn(__fmul_rn(x2, num),  1.48572235717979e-05f);
  num = __fadd_rn(__fmul_rn(x2, num),  6.37261928875436e-04f);
  num = __fadd_rn(__fmul_rn(x2, num),  4.89352455891786e-03f);
  num = __fmul_rn(xc, num);
  float den = 1.19825839466702e-06f;
  den = __fadd_rn(__fmul_rn(x2, den), 1.18534705686654e-04f);
  den = __fadd_rn(__fmul_rn(x2, den), 2.26843463243900e-03f);
  den = __fadd_rn(__fmul_rn(x2, den), 4.89352518554385e-03f);
  float r = __fdiv_rn(num, den);
  return (fabsf(x) < 0.0004f) ? x : r;
}

// XLA LogisticExpander: logistic(x) = 0.5 + 0.5*tanh(0.5*x), separate roundings
__device__ __forceinline__ float xla_sigmoid(float x){
  float t = xla_tanh(__fmul_rn(0.5f, x));
  return __fadd_rn(0.5f, __fmul_rn(0.5f, t));
}

// pack fp32 score + v; ties -> smaller v (first-max, matching jnp.argmax)
__device__ __forceinline__ unsigned long long pack32(float s, int v){
  uint32_t u = __float_as_uint(s);
  u = (u >> 31) ? ~u : (u | 0x80000000u);
  return ((unsigned long long)u << 32) | (unsigned)(8191 - v);
}

#define LGKM0 asm volatile("s_waitcnt lgkmcnt(0)" ::: "memory")

// ---------------- init ----------------
__global__ void initz(float* hfull, unsigned long long* best, int* flags){
  int i = blockIdx.x*256 + threadIdx.x;
  if (i < HH*BB)  hfull[i] = 0.f;          // slot 0 = h(-1) = 0
  if (i < TT*BB)  best[i] = 0ull;
  if (i < 256)    flags[i] = 0;
}

// ---------------- px precompute: px[t][e][b] = emb[x[b][t]][e] ----------------
__global__ __launch_bounds__(256) void pxgen(
    const int* __restrict__ x, const float* __restrict__ emb, float* __restrict__ px)
{
  int flat = blockIdx.x*256 + threadIdx.x;      // 128*256*64 = 2M
  int b = flat & 63;
  int e = (flat >> 6) & 255;
  int t = flat >> 14;
  if (t >= TT) return;
  int tok = x[b*TT + t];
  px[((size_t)t*EE + e)*BB + b] = emb[(size_t)tok*EE + e];
}

// ---------------- transpose 4 gate matrices: in [R][C] -> out[(g*C + c)*R + r] ----------------
__global__ __launch_bounds__(256) void transpose4f(
    const float* __restrict__ g0, const float* __restrict__ g1,
    const float* __restrict__ g2, const float* __restrict__ g3,
    float* __restrict__ out, int R, int C)
{
  const float* in = (blockIdx.y==0)?g0:(blockIdx.y==1)?g1:(blockIdx.y==2)?g2:g3;
  int tilesC = C >> 6;
  int tr = blockIdx.x / tilesC, tc = blockIdx.x % tilesC;
  __shared__ float tile[64][65];
  int tid = threadIdx.x;
  #pragma unroll
  for (int s = 0; s < 16; ++s) {
    int li = s*256 + tid;
    int r = li >> 6, c = li & 63;
    tile[r][c] = in[(size_t)(tr*64 + r)*C + tc*64 + c];
  }
  __syncthreads();
  #pragma unroll
  for (int s = 0; s < 16; ++s) {
    int li = s*256 + tid;
    int c = li >> 6, r = li & 63;
    out[((size_t)blockIdx.y*C + tc*64 + c)*R + tr*64 + r] = tile[r][c];
  }
}

// ---------------- cooperative LSTM recurrence: XLA-CPU faithful, panel-split k ------------
// R16 = R14 verbatim (the session's verified optimum: 4.98ms steady / 6244us e2e).
// hU MAC split along k by Eigen panels: wave kh = w>>2 (0: k<576 = panels P0,P1;
// 1: k>=576 = P2,P3), p = w&3 (j-column). Each thread computes ALL 4 gates over its
// k-half, so every h4 LDS read feeds 4 gates instead of 2 -> hU LDS read volume
// halves (the R13/R15 ablations proved LDS instrs on the critical path, not barriers,
// are the cost; the xw path is poll-overlapped and must stay LDS-staged -- R15's
// register-direct px regressed). Bit-exactness: fold structure T=fl(fl(fl(P0+P1)+P2)
// +P3) makes panels independent sub-chains; kh0 computes tA=fl(P0+P1), kh1 keeps
// P2,P3 separate; finalizers combine in exact fold order via xch. Transport: write-
// once hfull slots, agent stores + vmcnt-drain + release flag, plain cacheable
// consumer loads (first touch flag-gated). Raw s_barrier + lgkm-only waits in hot
// loop (prefetch vmcnt crosses barriers).
__global__ __launch_bounds__(512) void lstm_rec(
    const float* __restrict__ Wt, const float* __restrict__ Ut,
    const float* __restrict__ bi, const float* __restrict__ bf,
    const float* __restrict__ bog, const float* __restrict__ bc,
    const float* __restrict__ px, float* __restrict__ hfull,
    int* __restrict__ flags)
{
  __shared__ float sA[64*LSTRIDE];
  __shared__ float sB[64*LSTRIDE];
  __shared__ float spx[64*LSTRIDE];
  __shared__ float xch[2304];   // [0..1023] kh1->kh0 P2/P3 g0,g1 | [1024..1535] kh0->kh1 tA g2,g3
                                // [1536..2047] th/ogs exchange

  const int tid  = threadIdx.x;
  const int w    = tid >> 6;
  const int lane = tid & 63;
  const int p    = w & 3;                  // j-column 0..3
  const int kh   = w >> 2;                 // k-half: 0 = panels P0,P1 (k<576), 1 = P2,P3
  const int ju   = __builtin_amdgcn_readfirstlane(blockIdx.x*4 + p);
  const int sw4  = ((lane >> 3) & 7) << 2; // read-side column swizzle for row=lane

  // U rows for ALL 4 gates (uniform per wave -> scalar regs)
  const float* Ug0 = Ut + ((size_t)0*HH + ju)*HH;
  const float* Ug1 = Ut + ((size_t)1*HH + ju)*HH;
  const float* Ug2 = Ut + ((size_t)2*HH + ju)*HH;
  const float* Ug3 = Ut + ((size_t)3*HH + ju)*HH;
  // xw rows for my finalized gate pair (kh0: i,f ; kh1: og,c~)
  const int g0 = 2*kh, g1 = 2*kh + 1;
  const float* W0 = Wt + ((size_t)g0*HH + ju)*EE;
  const float* W1 = Wt + ((size_t)g1*HH + ju)*EE;
  const float biaA = kh ? bog[ju] : bi[ju];
  const float biaB = kh ? bc[ju]  : bf[ju];

  float c = 0.f;
  float B0 = 0.f, B1 = 0.f;   // xw+bias for my 2 finalized gates
  float4 pre[4];

  auto load_chunk = [&](const float* hp, int hcn){
    #pragma unroll
    for (int s = 0; s < 4; ++s) {
      int f = s*512 + tid;
      int k = f >> 4, b0 = (f & 15)*4;
      pre[s] = *(const float4*)(hp + (size_t)(hcn*128 + k)*BB + b0);
    }
  };
  auto store_chunk = [&](float* buf){
    #pragma unroll
    for (int s = 0; s < 4; ++s) {
      int f = s*512 + tid;
      int k = f >> 4, b0 = (f & 15)*4;
      int kc = k ^ (((b0 >> 3) & 7) << 2);
      buf[(b0+0)*LSTRIDE + kc] = pre[s].x;
      buf[(b0+1)*LSTRIDE + kc] = pre[s].y;
      buf[(b0+2)*LSTRIDE + kc] = pre[s].z;
      buf[(b0+3)*LSTRIDE + kc] = pre[s].w;
    }
  };

  // xw chains for my 2 gates at step t2 (exact e=0..255 mul/add order, then +bias)
  auto compute_xw = [&](int t2){
    float A0 = 0.f, A1 = 0.f;
    #pragma unroll 1
    for (int ch = 0; ch < 2; ++ch) {
      const float* pxc = px + ((size_t)t2*EE + ch*128)*BB;
      LGKM0;                                  // prior spx readers retired (program order)
      __builtin_amdgcn_s_barrier();           // WAR: all waves done reading spx
      #pragma unroll
      for (int s = 0; s < 4; ++s) {
        int f = s*512 + tid;
        int e = f >> 4, b0 = (f & 15)*4;
        float4 v = *(const float4*)(pxc + (size_t)e*BB + b0);
        int ec = e ^ (((b0 >> 3) & 7) << 2);
        spx[(b0+0)*LSTRIDE + ec] = v.x;
        spx[(b0+1)*LSTRIDE + ec] = v.y;
        spx[(b0+2)*LSTRIDE + ec] = v.z;
        spx[(b0+3)*LSTRIDE + ec] = v.w;
      }
      LGKM0;                                  // staging writes retired
      __builtin_amdgcn_s_barrier();           // RAW: spx visible to all waves
      #pragma unroll
      for (int e = 0; e < 128; e += 4) {
        float4 p4 = *(const float4*)&spx[lane*LSTRIDE + (e ^ sw4)];
        A0 = __fadd_rn(A0, __fmul_rn(p4.x, W0[ch*128 + e + 0]));
        A1 = __fadd_rn(A1, __fmul_rn(p4.x, W1[ch*128 + e + 0]));
        A0 = __fadd_rn(A0, __fmul_rn(p4.y, W0[ch*128 + e + 1]));
        A1 = __fadd_rn(A1, __fmul_rn(p4.y, W1[ch*128 + e + 1]));
        A0 = __fadd_rn(A0, __fmul_rn(p4.z, W0[ch*128 + e + 2]));
        A1 = __fadd_rn(A1, __fmul_rn(p4.z, W1[ch*128 + e + 2]));
        A0 = __fadd_rn(A0, __fmul_rn(p4.w, W0[ch*128 + e + 3]));
        A1 = __fadd_rn(A1, __fmul_rn(p4.w, W1[ch*128 + e + 3]));
      }
    }
    B0 = __fadd_rn(A0, biaA);
    B1 = __fadd_rn(A1, biaB);
  };

  compute_xw(0);   // prologue: xw for t=0

  #pragma unroll 1
  for (int t = 0; t < TT; ++t) {
    const float* hp = hfull + (size_t)t*(HH*BB);        // h(t-1), write-once slot
    float*       rn = hfull + (size_t)(t+1)*(HH*BB);    // h(t) destination

    // ---- h @ U: panel-split MAC, all 4 gates per thread over my k-half ----
    load_chunk(hp, 0);
    float R0=0.f, R1=0.f, R2=0.f, R3=0.f;       // running panel chains (4 gates)
    float PA0=0.f, PA1=0.f, PA2=0.f, PA3=0.f;   // saved first panel of my half
    #pragma unroll 1
    for (int hc = 0; hc < 8; ++hc) {
      float* cur = (hc & 1) ? sB : sA;
      store_chunk(cur);                    // waits pre deps (counted vmcnt, not 0)
      if (hc < 7) load_chunk(hp, hc + 1);  // prefetch stays in flight across barrier
      LGKM0;                               // staging writes retired
      __builtin_amdgcn_s_barrier();        // (WAR on cur guaranteed by bar(hc-1))
      // my sub-range: kh0 -> k<576 (chunks 0..3 full, chunk4 subs 0,1);
      //               kh1 -> k>=576 (chunk4 subs 2,3, chunks 5..7 full)
      int sLo = kh ? ((hc == 4) ? 2 : (hc > 4 ? 0 : 4)) : 0;
      int sHi = kh ? ((hc >= 4) ? 4 : 0)               : ((hc < 4) ? 4 : (hc == 4 ? 2 : 0));
      #pragma unroll
      for (int sub = 0; sub < 4; ++sub) {
        if (sub < sLo || sub >= sHi) continue;     // wave-uniform guard
        int kabs = hc*128 + sub*32;
        if (kabs == 288 || kabs == 864) {          // end of my half's first panel
          PA0 = R0; R0 = 0.f;
          PA1 = R1; R1 = 0.f;
          PA2 = R2; R2 = 0.f;
          PA3 = R3; R3 = 0.f;
        }
        #pragma unroll
        for (int q = sub*32; q < sub*32 + 32; q += 4) {
          float4 h4 = *(const float4*)&cur[lane*LSTRIDE + (q ^ sw4)];
          int k = hc*128 + q;
          R0 = __fadd_rn(R0, __fmul_rn(h4.x, Ug0[k+0]));
          R1 = __fadd_rn(R1, __fmul_rn(h4.x, Ug1[k+0]));
          R2 = __fadd_rn(R2, __fmul_rn(h4.x, Ug2[k+0]));
          R3 = __fadd_rn(R3, __fmul_rn(h4.x, Ug3[k+0]));
          R0 = __fadd_rn(R0, __fmul_rn(h4.y, Ug0[k+1]));
          R1 = __fadd_rn(R1, __fmul_rn(h4.y, Ug1[k+1]));
          R2 = __fadd_rn(R2, __fmul_rn(h4.y, Ug2[k+1]));
          R3 = __fadd_rn(R3, __fmul_rn(h4.y, Ug3[k+1]));
          R0 = __fadd_rn(R0, __fmul_rn(h4.z, Ug0[k+2]));
          R1 = __fadd_rn(R1, __fmul_rn(h4.z, Ug1[k+2]));
          R2 = __fadd_rn(R2, __fmul_rn(h4.z, Ug2[k+2]));
          R3 = __fadd_rn(R3, __fmul_rn(h4.z, Ug3[k+2]));
          R0 = __fadd_rn(R0, __fmul_rn(h4.w, Ug0[k+3]));
          R1 = __fadd_rn(R1, __fmul_rn(h4.w, Ug1[k+3]));
          R2 = __fadd_rn(R2, __fmul_rn(h4.w, Ug2[k+3]));
          R3 = __fadd_rn(R3, __fmul_rn(h4.w, Ug3[k+3]));
        }
      }
    }
    // ---- exchange A: assemble T per gate in exact fold order ----
    // kh0: PA=P0, R=P1 -> tA = fl(P0+P1); publishes tA for gates 2,3; keeps 0,1
    // kh1: PA=P2, R=P3 (kept separate); publishes P2,P3 for gates 0,1; keeps 2,3
    float keepA = 0.f, keepB = 0.f, keepC = 0.f, keepD = 0.f;
    if (kh == 0) {
      keepA = __fadd_rn(PA0, R0);       // tA g0
      keepB = __fadd_rn(PA1, R1);       // tA g1
      xch[1024 + p*64 + lane] = __fadd_rn(PA2, R2);   // tA g2
      xch[1280 + p*64 + lane] = __fadd_rn(PA3, R3);   // tA g3
    } else {
      keepA = PA2; keepB = R2;          // P2,P3 g2
      keepC = PA3; keepD = R3;          // P2,P3 g3
      xch[   0 + p*64 + lane] = PA0;    // P2 g0
      xch[ 256 + p*64 + lane] = R0;     // P3 g0
      xch[ 512 + p*64 + lane] = PA1;    // P2 g1
      xch[ 768 + p*64 + lane] = R1;     // P3 g1
    }
    LGKM0;
    __builtin_amdgcn_s_barrier();       // exchange A visible
    float z0, z1;
    if (kh == 0) {
      float T0 = __fadd_rn(__fadd_rn(keepA, xch[   0 + p*64 + lane]), xch[ 256 + p*64 + lane]);
      float T1 = __fadd_rn(__fadd_rn(keepB, xch[ 512 + p*64 + lane]), xch[ 768 + p*64 + lane]);
      z0 = __fadd_rn(B0, T0);           // gate i
      z1 = __fadd_rn(B1, T1);           // gate f
    } else {
      float T2 = __fadd_rn(__fadd_rn(xch[1024 + p*64 + lane], keepA), keepB);
      float T3 = __fadd_rn(__fadd_rn(xch[1280 + p*64 + lane], keepC), keepD);
      z0 = __fadd_rn(B0, T2);           // gate og
      z1 = __fadd_rn(B1, T3);           // gate c~
    }

    // ---- gates: kh1 computes tanh(zc), sig(zo); kh0 computes sig(zi), sig(zf) ----
    float igv = 0.f, fgv = 0.f, hv = 0.f;
    if (kh) {
      float th  = xla_tanh(z1);
      float ogs = xla_sigmoid(z0);
      xch[1536 + p*64 + lane] = th;
      xch[1792 + p*64 + lane] = ogs;
    } else {
      igv = xla_sigmoid(z0);
      fgv = xla_sigmoid(z1);
    }
    LGKM0;
    __builtin_amdgcn_s_barrier();           // th/ogs visible (LDS-only hazard)
    if (!kh) {
      float th  = xch[1536 + p*64 + lane];
      float ogs = xch[1792 + p*64 + lane];
      c = __fadd_rn(__fmul_rn(fgv, c), __fmul_rn(igv, th));
      hv = __fmul_rn(ogs, xla_tanh(c));
      __hip_atomic_store(&rn[(size_t)ju*BB + lane], hv,
                         __ATOMIC_RELAXED, __HIP_MEMORY_SCOPE_AGENT);
    }
    __syncthreads();   // REQUIRED vmcnt(0) drain: all waves' h stores done before flag
    if (tid == 0)
      __hip_atomic_store(&flags[blockIdx.x], t+1, __ATOMIC_RELEASE, __HIP_MEMORY_SCOPE_AGENT);

    if (t < TT-1) {
      compute_xw(t+1);    // overlapped with other blocks finishing step t
      if (w == 0) {       // wave0 polls all 256 flags (4 per lane)
        for (;;) {
          int m0 = __hip_atomic_load(&flags[lane],       __ATOMIC_RELAXED, __HIP_MEMORY_SCOPE_AGENT);
          int m1 = __hip_atomic_load(&flags[64 + lane],  __ATOMIC_RELAXED, __HIP_MEMORY_SCOPE_AGENT);
          int m2 = __hip_atomic_load(&flags[128 + lane], __ATOMIC_RELAXED, __HIP_MEMORY_SCOPE_AGENT);
          int m3 = __hip_atomic_load(&flags[192 + lane], __ATOMIC_RELAXED, __HIP_MEMORY_SCOPE_AGENT);
          int mm = m0 < m1 ? m0 : m1;
          int nn = m2 < m3 ? m2 : m3;
          mm = mm < nn ? mm : nn;
          if (__all(mm >= t+1)) break;
          __builtin_amdgcn_s_sleep(1);
        }
        __atomic_signal_fence(__ATOMIC_ACQUIRE);
      }
      __syncthreads();
    }
  }
}

// ---------------- logits + gumbel argmax: XLA-CPU faithful (reads hfull slot t+1) -------
__global__ __launch_bounds__(256, 2) void logits_samp(
    const float* __restrict__ hfull, const float* __restrict__ Wo,
    const float* __restrict__ bo, const int* __restrict__ gnp,
    unsigned long long* __restrict__ best)
{
  const int t = 64 + blockIdx.y;
  if (t < gnp[0]) return;
  const int vt   = blockIdx.x;     // [0,8)
  const int z    = blockIdx.z;     // [0,4) b-quarter
  const int tid  = threadIdx.x;
  const int w    = tid >> 6;
  const int lane = tid & 63;

  int v[4], vc[4]; bool val[4];
  #pragma unroll
  for (int vj = 0; vj < 4; ++vj) {
    v[vj]  = vt*1024 + vj*256 + tid;
    val[vj] = (v[vj] < VV);
    vc[vj] = val[vj] ? v[vj] : (VV-1);
  }

  __shared__ float hds[128*16];
  __shared__ unsigned long long red[4][16];

  float tot[64], reg[64];
  #pragma unroll
  for (int i = 0; i < 64; ++i) { tot[i] = 0.f; reg[i] = 0.f; }

  const float* hf = hfull + (size_t)(t+1)*(HH*BB);   // h(t) lives in slot t+1

  #pragma unroll 1
  for (int kc8 = 0; kc8 < 8; ++kc8) {
    __syncthreads();
    #pragma unroll
    for (int s = 0; s < 8; ++s) {
      int idx = s*256 + tid;
      int kl = idx >> 4, bb = idx & 15;
      hds[idx] = hf[(size_t)(kc8*128 + kl)*BB + z*16 + bb];
    }
    __syncthreads();
    #pragma unroll 1
    for (int sub = 0; sub < 4; ++sub) {
      int kabs = kc8*128 + sub*32;
      if (kabs == 288 || kabs == 576 || kabs == 864) {
        #pragma unroll
        for (int i = 0; i < 64; ++i) { tot[i] = __fadd_rn(tot[i], reg[i]); reg[i] = 0.f; }
      }
      #pragma unroll 2
      for (int k = sub*32; k < sub*32 + 32; ++k) {
        const float* wr = Wo + (size_t)(kc8*128 + k)*VV;
        float wv0 = wr[vc[0]], wv1 = wr[vc[1]], wv2 = wr[vc[2]], wv3 = wr[vc[3]];
        #pragma unroll
        for (int bb = 0; bb < 16; ++bb) {
          float hb = hds[k*16 + bb];
          reg[0*16+bb] = __fadd_rn(reg[0*16+bb], __fmul_rn(hb, wv0));
          reg[1*16+bb] = __fadd_rn(reg[1*16+bb], __fmul_rn(hb, wv1));
          reg[2*16+bb] = __fadd_rn(reg[2*16+bb], __fmul_rn(hb, wv2));
          reg[3*16+bb] = __fadd_rn(reg[3*16+bb], __fmul_rn(hb, wv3));
        }
      }
    }
  }
  #pragma unroll
  for (int i = 0; i < 64; ++i) tot[i] = __fadd_rn(tot[i], reg[i]);

  uint32_t kt0, kt1;
  tf2x32(0u, 1u, 0u, (uint32_t)t, kt0, kt1);
  float bov[4];
  #pragma unroll
  for (int vj = 0; vj < 4; ++vj) bov[vj] = val[vj] ? bo[v[vj]] : 0.f;

  #pragma unroll 1
  for (int bb = 0; bb < 16; ++bb) {
    int bglob = z*16 + bb;
    unsigned long long pm = 0ull;
    #pragma unroll
    for (int vj = 0; vj < 4; ++vj) {
      if (val[vj]) {
        uint32_t y0, y1;
        tf2x32(kt0, kt1, 0u, (uint32_t)(bglob*VV + v[vj]), y0, y1);
        float u  = u01f(y0 ^ y1);
        float l1 = logf(u);
        float l2 = logf(-l1);
        float g  = -l2;
        float L  = __fadd_rn(tot[vj*16 + bb], bov[vj]);
        float sc = __fadd_rn(g, L);
        unsigned long long pk = pack32(sc, v[vj]);
        if (pk > pm) pm = pk;
      }
    }
    #pragma unroll
    for (int m = 32; m > 0; m >>= 1) {
      unsigned long long q = __shfl_xor(pm, m);
      if (q > pm) pm = q;
    }
    if (lane == 0) red[w][bb] = pm;
    __syncthreads();
    if (tid == 0) {
      unsigned long long m0 = red[0][bb];
      if (red[1][bb] > m0) m0 = red[1][bb];
      if (red[2][bb] > m0) m0 = red[2][bb];
      if (red[3][bb] > m0) m0 = red[3][bb];
      atomicMax(&best[(size_t)t*BB + z*16 + bb], m0);
    }
    __syncthreads();
  }
}

// ---------------- finalize ----------------
__global__ void finalize(const int* __restrict__ x, const int* __restrict__ gnp,
                         const unsigned long long* __restrict__ best, int* __restrict__ out)
{
  int i = blockIdx.x*256 + threadIdx.x;
  if (i >= BB*TT) return;
  int t = i & 127;
  int b = i >> 7;
  if (t < gnp[0] || t < 64) out[i] = x[i];
  else out[i] = 8191 - (int)(best[(size_t)t*BB + b] & 0x1FFFull);
}

// ---------------- launch ----------------
extern "C" void kernel_launch(void* const* d_in, const int* in_sizes, int n_in,
                              void* d_out, int out_size, void* d_ws, size_t ws_size,
                              hipStream_t stream)
{
  const int*   x    = (const int*)  d_in[0];
  const int*   gn   = (const int*)  d_in[1];
  const float* emb  = (const float*)d_in[2];
  const float* Wi   = (const float*)d_in[3];
  const float* Ui   = (const float*)d_in[4];
  const float* bi   = (const float*)d_in[5];
  const float* Wf   = (const float*)d_in[6];
  const float* Uf   = (const float*)d_in[7];
  const float* bf   = (const float*)d_in[8];
  const float* Wog  = (const float*)d_in[9];
  const float* Uog  = (const float*)d_in[10];
  const float* bog  = (const float*)d_in[11];
  const float* Wc   = (const float*)d_in[12];
  const float* Uc   = (const float*)d_in[13];
  const float* bc   = (const float*)d_in[14];
  const float* Wo   = (const float*)d_in[15];
  const float* bo   = (const float*)d_in[16];

  // ws: Ut 16MB | Wt 4MB | hfull 32.25MB (129 write-once h slots; doubles as hist)
  //     | px 8MB | best 64KB | flags 1KB   (~60.3MB total)
  float* Ut    = (float*)d_ws;                             // 4Mi floats
  float* Wt    = Ut + (size_t)4*1024*1024;                 // 1Mi floats
  float* hfull = Wt + (size_t)1024*1024;                   // 129*65536 floats
  float* px    = hfull + (size_t)(TT+1)*HH*BB;             // 128*256*64 floats
  unsigned long long* best =
      (unsigned long long*)(px + (size_t)TT*EE*BB);        // 8192 u64
  int* flags  = (int*)(best + (size_t)TT*BB);              // 256 int

  initz<<<512, 256, 0, stream>>>(hfull, best, flags);
  transpose4f<<<dim3(256,4), 256, 0, stream>>>(Ui, Uf, Uog, Uc, Ut, 1024, 1024);
  transpose4f<<<dim3(64,4),  256, 0, stream>>>(Wi, Wf, Wog, Wc, Wt, 256, 1024);
  pxgen<<<8192, 256, 0, stream>>>(x, emb, px);

  const float* Wtp = Wt; const float* Utp = Ut;
  const float* bip = bi; const float* bfp = bf; const float* bogp = bog; const float* bcp = bc;
  const float* pxp = px; float* hfullp = hfull; int* flagsp = flags;
  void* kargs[] = { (void*)&Wtp, (void*)&Utp,
                    (void*)&bip, (void*)&bfp, (void*)&bogp, (void*)&bcp,
                    (void*)&pxp, (void*)&hfullp, (void*)&flagsp };
  hipLaunchCooperativeKernel((void*)lstm_rec, dim3(256), dim3(512), kargs, 0, stream);

  logits_samp<<<dim3(8,64,4), 256, 0, stream>>>(hfull, Wo, bo, gn, best);
  finalize<<<32, 256, 0, stream>>>(x, gn, best, (int*)d_out);
}